// Round 1
// baseline (498.264 us; speedup 1.0000x reference)
//
#include <hip/hip_runtime.h>

// ---------------------------------------------------------------------------
// AdderNet decoder: chain of L1-distance "convs" + ReLU/BN + 2x unpool.
// All intermediates live padded in d_ws: (N, C, H+2, W+4), interior at (1,1),
// borders zeroed by one hipMemsetAsync per launch. Padding contributes
// |0 - w| exactly like the reference's zero-pad.
// ---------------------------------------------------------------------------

__global__ __launch_bounds__(256) void pad_copy_k(
    const float* __restrict__ in, float* __restrict__ out,
    int NC, int H, int W)
{
    int i = blockIdx.x * 256 + threadIdx.x;
    int total = NC * H * W;
    if (i >= total) return;
    int w_ = i % W;
    int t  = i / W;
    int h  = t % H;
    int nc = t / H;
    int wpad = W + 4;
    out[((size_t)nc * (H + 2) + (h + 1)) * wpad + (w_ + 1)] = in[i];
}

// unpool + relu + bn fused. Non-selected positions get relu(0)*w+b = b.
__global__ __launch_bounds__(256) void unpool_k(
    const float* __restrict__ in,   // (N,C,H,W) flat
    const int*   __restrict__ locs, // (N,C,H,W) -> flat idx into (2H x 2W)
    const float* __restrict__ bw, const float* __restrict__ bb,
    float* __restrict__ out,        // padded (N,C,2H+2,2W+4)
    int C, int H, int W, int N)
{
    int i = blockIdx.x * 256 + threadIdx.x;
    int total = N * C * H * W;
    if (i >= total) return;
    int w_ = i % W;
    int t  = i / W;
    int h  = t % H; t /= H;
    int c  = t % C;
    int n  = t / C;
    float v  = in[i];
    int   id = locs[i];
    int Wo = 2 * W;
    int ho = id / Wo, wo = id % Wo;
    float scale = bw[c], bias = bb[c];
    float val = fmaxf(v, 0.f) * scale + bias;
    int wpad = Wo + 4;
    float* ob = out + (size_t)(n * C + c) * (2 * H + 2) * wpad;
    int h0 = 2 * h, w0 = 2 * w_;
#pragma unroll
    for (int dy = 0; dy < 2; ++dy)
#pragma unroll
        for (int dx = 0; dx < 2; ++dx) {
            float x = (h0 + dy == ho && w0 + dx == wo) ? val : bias;
            ob[(size_t)(h0 + dy + 1) * wpad + (w0 + dx + 1)] = x;
        }
}

// L1-distance "adder conv". Input padded (N,CIN,H+2,W+4). Each thread computes
// a STRIP-wide horizontal strip of one output row for one (n, co).
// Optional fused relu+bn epilogue; output either padded (feeds next adder)
// or flat (feeds unpool / final output).
template <int CIN, int STRIP, bool BN, bool OUT_PADDED>
__global__ __launch_bounds__(256) void adder_k(
    const float* __restrict__ xin, const float* __restrict__ w,
    const float* __restrict__ bnw, const float* __restrict__ bnb,
    float* __restrict__ out,
    int H, int W, int COUT, int SB)
{
    const int wpad = W + 4;
    int b = blockIdx.x;
    const int sb = b % SB;  b /= SB;
    const int co = b % COUT; b /= COUT;
    const int n  = b;

    const int s  = sb * 256 + (int)threadIdx.x;       // strip index
    const int spr = W / STRIP;                        // strips per row
    const int r  = s / spr;                           // output row
    const int c0 = (s - r * spr) * STRIP;             // padded col of window
    if (r >= H) return;

    const int chstride = (H + 2) * wpad;
    const float* xb = xin + (size_t)(n * CIN) * chstride + (size_t)r * wpad + c0;
    const float* wp = w + (size_t)co * CIN * 9;

    float acc[STRIP];
#pragma unroll
    for (int p = 0; p < STRIP; ++p) acc[p] = 0.f;

    for (int ci = 0; ci < CIN; ++ci) {
        const float* xc = xb + (size_t)ci * chstride;
        const float* wc = wp + ci * 9;
        float wv[9];
#pragma unroll
        for (int k = 0; k < 9; ++k) wv[k] = wc[k];    // wave-uniform -> s_load
#pragma unroll
        for (int di = 0; di < 3; ++di) {
            const float* row = xc + di * wpad;        // 16B-aligned
            float xr[STRIP + 2];
            const float4 v0 = *reinterpret_cast<const float4*>(row);
            xr[0] = v0.x; xr[1] = v0.y; xr[2] = v0.z; xr[3] = v0.w;
            if constexpr (STRIP == 8) {
                const float4 v1 = *reinterpret_cast<const float4*>(row + 4);
                xr[4] = v1.x; xr[5] = v1.y; xr[6] = v1.z; xr[7] = v1.w;
                const float2 v2 = *reinterpret_cast<const float2*>(row + 8);
                xr[8] = v2.x; xr[9] = v2.y;
            } else {
                const float2 v2 = *reinterpret_cast<const float2*>(row + 4);
                xr[4] = v2.x; xr[5] = v2.y;
            }
#pragma unroll
            for (int dj = 0; dj < 3; ++dj) {
                const float wvv = wv[di * 3 + dj];
#pragma unroll
                for (int p = 0; p < STRIP; ++p)
                    acc[p] -= fabsf(xr[p + dj] - wvv); // v_sub + v_sub(abs) = 2 VALU/tap
            }
        }
    }

    float scale = 1.f, bias = 0.f;
    if constexpr (BN) { scale = bnw[co]; bias = bnb[co]; }

    size_t o;
    if constexpr (OUT_PADDED)
        o = ((size_t)(n * COUT + co) * (H + 2) + (r + 1)) * wpad + (c0 + 1);
    else
        o = ((size_t)(n * COUT + co) * H + (size_t)r) * W + c0;

#pragma unroll
    for (int p = 0; p < STRIP; ++p) {
        float v = acc[p];
        if constexpr (BN) v = fmaxf(v, 0.f) * scale + bias;
        out[o + p] = v;
    }
}

// ---------------------------------------------------------------------------

extern "C" void kernel_launch(void* const* d_in, const int* in_sizes, int n_in,
                              void* d_out, int out_size, void* d_ws, size_t ws_size,
                              hipStream_t stream)
{
    const float* x      = (const float*)d_in[0];
    // d_in[1] = layer, d_in[2] = activation_idx : unused by the reference
    const int*   locs13 = (const int*)d_in[3];
    const int*   locs6  = (const int*)d_in[4];
    const float* w3  = (const float*)d_in[5];
    const float* w6  = (const float*)d_in[6];
    const float* w9  = (const float*)d_in[7];
    const float* w12 = (const float*)d_in[8];
    const float* w16 = (const float*)d_in[9];
    const float* w19 = (const float*)d_in[10];
    const float* w23 = (const float*)d_in[11];
    const float* w26 = (const float*)d_in[12];
    const float* bn5w  = (const float*)d_in[13], *bn5b  = (const float*)d_in[14];
    const float* bn8w  = (const float*)d_in[15], *bn8b  = (const float*)d_in[16];
    const float* bn11w = (const float*)d_in[17], *bn11b = (const float*)d_in[18];
    const float* bn15w = (const float*)d_in[19], *bn15b = (const float*)d_in[20];
    const float* bn18w = (const float*)d_in[21], *bn18b = (const float*)d_in[22];
    const float* bn22w = (const float*)d_in[23], *bn22b = (const float*)d_in[24];
    const float* bn25w = (const float*)d_in[25], *bn25b = (const float*)d_in[26];

    float* ws = (float*)d_ws;
    // padded buffer sizes (floats):
    //   32x32x128ch : 4*128*34*36 = 626688
    //   64x64x64ch  : 4*64*66*68  = 1148928
    //   128x128x32ch: 4*32*130*132= 2196480
    float* B0 = ws;                  // 626688
    float* B1 = ws + 626688;         // 626688
    float* B2 = ws + 1253376;        // 626688
    float* B3 = ws + 1880064;        // 1148928
    float* B4 = ws + 3028992;        // 1148928
    float* B5 = ws + 4177920;        // 2196480
    float* B6 = ws + 6374400;        // 2196480
    const size_t WS_BYTES = (size_t)8570880 * sizeof(float); // ~34.3 MB

    hipMemsetAsync(d_ws, 0, WS_BYTES, stream);

    // x -> B0 (padded)
    pad_copy_k<<<2048, 256, 0, stream>>>(x, B0, 4 * 128, 32, 32);

    // L3 : adder(x,w3) + relu + bn5          (4,128,32,32)
    adder_k<128, 4, true,  true ><<<512, 256, 0, stream>>>(B0, w3,  bn5w,  bn5b,  B1, 32, 32, 128, 1);
    // L6 : + relu+bn8
    adder_k<128, 4, true,  true ><<<512, 256, 0, stream>>>(B1, w6,  bn8w,  bn8b,  B2, 32, 32, 128, 1);
    // L9 : + relu+bn11
    adder_k<128, 4, true,  true ><<<512, 256, 0, stream>>>(B2, w9,  bn11w, bn11b, B0, 32, 32, 128, 1);
    // L12: adder -> (4,64,32,32) flat (no activation before unpool)
    adder_k<128, 4, false, false><<<256, 256, 0, stream>>>(B0, w12, nullptr, nullptr, B1, 32, 32, 64, 1);
    // unpool13 + relu + bn15 -> (4,64,66,68) padded
    unpool_k<<<1024, 256, 0, stream>>>(B1, locs13, bn15w, bn15b, B3, 64, 32, 32, 4);
    // L16: + relu+bn18                       (4,64,64,64)
    adder_k<64, 8, true,  true ><<<512, 256, 0, stream>>>(B3, w16, bn18w, bn18b, B4, 64, 64, 64, 2);
    // L19: adder -> (4,32,64,64) flat
    adder_k<64, 8, false, false><<<256, 256, 0, stream>>>(B4, w19, nullptr, nullptr, B3, 64, 64, 32, 2);
    // unpool6 + relu + bn22 -> (4,32,130,132) padded
    unpool_k<<<2048, 256, 0, stream>>>(B3, locs6, bn22w, bn22b, B5, 32, 64, 64, 4);
    // L23: + relu+bn25                       (4,32,128,128)
    adder_k<32, 8, true,  true ><<<1024, 256, 0, stream>>>(B5, w23, bn25w, bn25b, B6, 128, 128, 32, 8);
    // L26: final adder -> d_out (4,3,128,128) flat
    adder_k<32, 8, false, false><<<96, 256, 0, stream>>>(B6, w26, nullptr, nullptr, (float*)d_out, 128, 128, 3, 8);
}